// Round 8
// baseline (110.986 us; speedup 1.0000x reference)
//
#include <hip/hip_runtime.h>

typedef __attribute__((ext_vector_type(8))) short short8;
typedef __attribute__((ext_vector_type(4))) float f32x4;
typedef __attribute__((ext_vector_type(4))) unsigned short ushort4_t;
typedef unsigned short ushort_t;
typedef unsigned long long u64;

#define D_MODEL 768
#define NHEAD 12
#define HD 64
#define BATCH 4
#define HWIDTH 32
#define HW 1024
#define TOK (BATCH*HW)
#define QKV_N (3*D_MODEL)
#define BH (BATCH*NHEAD)
#define QSCALE 0.18033688f  /* 0.125 * log2(e) */

__device__ __forceinline__ ushort_t f2bf(float f) {
    union { float f; unsigned u; } v; v.f = f;
    unsigned u = v.u;
    unsigned r = u + 0x7FFFu + ((u >> 16) & 1u);
    return (ushort_t)(r >> 16);
}
__device__ __forceinline__ float bf2f(ushort_t h) {
    union { unsigned u; float f; } v; v.u = ((unsigned)h) << 16;
    return v.f;
}
__device__ __forceinline__ float ex2(float x) {
    float r; asm("v_exp_f32 %0, %1" : "=v"(r) : "v"(x)); return r;
}
__device__ __forceinline__ unsigned cvtpk(float lo, float hi) {
    unsigned r; asm("v_cvt_pk_bf16_f32 %0, %1, %2" : "=v"(r) : "v"(lo), "v"(hi)); return r;
}

// ---------------- RMSNorm: one wave per token ----------------
__global__ void rmsnorm_kernel(const float* __restrict__ x, const float* __restrict__ gamma,
                               ushort_t* __restrict__ xn) {
    int wave = threadIdx.x >> 6, lane = threadIdx.x & 63;
    int t = blockIdx.x * 4 + wave;
    const float* xr = x + (size_t)t * D_MODEL;
    float v[12]; float ss = 0.f;
    #pragma unroll
    for (int j = 0; j < 12; ++j) { v[j] = xr[lane + j*64]; ss += v[j]*v[j]; }
    #pragma unroll
    for (int m = 1; m < 64; m <<= 1) ss += __shfl_xor(ss, m, 64);
    float r = rsqrtf(ss * (1.f/768.f) + 1e-6f);
    ushort_t* o = xn + (size_t)t * D_MODEL;
    #pragma unroll
    for (int j = 0; j < 12; ++j) o[lane + j*64] = f2bf(v[j] * r * gamma[lane + j*64]);
}

// ---------------- f32 -> bf16 convert ----------------
__global__ void cvt_kernel(const float* __restrict__ in, ushort_t* __restrict__ out, int n) {
    int i = blockIdx.x * blockDim.x + threadIdx.x;
    if (i < n) out[i] = f2bf(in[i]);
}

// ---------------- axial RoPE sin/cos tables (1024 x 32) ----------------
__global__ void sincos_kernel(float* __restrict__ sint, float* __restrict__ cost) {
    int i = blockIdx.x * blockDim.x + threadIdx.x; // 32768
    int p = i >> 5, j = i & 31;
    int r = p >> 5, c = p & 31;
    int jj = j & 15;
    float freq = powf(10000.f, -(float)(2*jj) / 32.f);
    float pos = (j < 16) ? (float)r : (float)c;
    float th = pos * freq;
    sint[i] = sinf(th);
    cost[i] = cosf(th);
}

// ---------------- barrier-free 1-wave 64x64 GEMM, 3-deep counted-vmcnt ----------------
// C[4096, 64*NT] = A[4096,768] * B[64*NT,768]^T.  EPI: 0 = fused RoPE/V-layout, 1 = f32 out.
// Block mapping: 8 L2-sized chunks (XCD-aligned), chunk = 16 mtiles x NT/2 ntiles.
template<int NT, int EPI>
__global__ __launch_bounds__(64, 2) void gemm64(const ushort_t* __restrict__ A,
                                                const ushort_t* __restrict__ B,
                                                const float* __restrict__ sint,
                                                const float* __restrict__ cost,
                                                ushort_t* __restrict__ Qr,
                                                ushort_t* __restrict__ Kr,
                                                ushort_t* __restrict__ VTt,
                                                float* __restrict__ C) {
    __shared__ ushort_t As[4][64*32];
    __shared__ ushort_t Bs[4][64*32];
    const int K = 768;
    const int CNT = NT / 2;
    int c = blockIdx.x & 7;              // chunk -> XCD
    int l = blockIdx.x >> 3;             // 0..16*CNT-1
    int cm = c >> 1, cn = c & 1;
    int mtile = cm*16 + l / CNT;
    int ntile = cn*CNT + l % CNT;
    int tm = mtile * 64, tn = ntile * 64;
    int lane = threadIdx.x;
    int l15 = lane & 15, l4 = lane >> 4;

    // staging: per issue j (0..3), 64 lanes x 16B; HW scatters to base + lane*16B.
    // source slot pre-swizzled so LDS-linear layout realizes slot' = slot ^ (row&3).
    int srow = lane >> 2;
    int sslot = (lane & 3) ^ (srow & 3);
    const ushort_t* Abase = A + (size_t)(tm + srow)*K + sslot*8;
    const ushort_t* Bbase = B + (size_t)(tn + srow)*K + sslot*8;

    auto issue = [&](int buf, int k0) {
        #pragma unroll
        for (int j = 0; j < 4; ++j) {
            const ushort_t* ga = Abase + (size_t)(j*16)*K + k0;
            __builtin_amdgcn_global_load_lds((const __attribute__((address_space(1))) void*)ga,
                (__attribute__((address_space(3))) void*)(&As[buf][j*512]), 16, 0, 0);
            const ushort_t* gb = Bbase + (size_t)(j*16)*K + k0;
            __builtin_amdgcn_global_load_lds((const __attribute__((address_space(1))) void*)gb,
                (__attribute__((address_space(3))) void*)(&Bs[buf][j*512]), 16, 0, 0);
        }
    };

    // fragment read: row = i*16 + l15, slot = l4 ^ (l15&3)
    int frag_off = l15*32 + (l4 ^ (l15 & 3))*8;
    f32x4 acc[4][4] = {};

    auto compute = [&](int bi) {
        short8 af[4], bfr[4];
        #pragma unroll
        for (int i = 0; i < 4; ++i) af[i]  = *(const short8*)&As[bi][i*512 + frag_off];
        #pragma unroll
        for (int i = 0; i < 4; ++i) bfr[i] = *(const short8*)&Bs[bi][i*512 + frag_off];
        #pragma unroll
        for (int mi = 0; mi < 4; ++mi)
            #pragma unroll
            for (int ni = 0; ni < 4; ++ni)
                acc[mi][ni] = __builtin_amdgcn_mfma_f32_16x16x32_bf16(af[mi], bfr[ni], acc[mi][ni], 0, 0, 0);
    };

    issue(0, 0); issue(1, 32); issue(2, 64);
    for (int t = 0; t < 21; ++t) {
        asm volatile("s_waitcnt vmcnt(16)" ::: "memory");
        issue((t+3) & 3, (t+3)*32);
        compute(t & 3);
    }
    asm volatile("s_waitcnt vmcnt(16)" ::: "memory"); compute(1);
    asm volatile("s_waitcnt vmcnt(8)"  ::: "memory"); compute(2);
    asm volatile("s_waitcnt vmcnt(0)"  ::: "memory"); compute(3);

    if constexpr (EPI == 0) {
        int region = ntile / 12;        // 0=Q 1=K 2=V
        int h = ntile % 12;
        if (region < 2) {
            ushort_t* dst = (region == 0) ? Qr : Kr;
            float scale = (region == 0) ? QSCALE : 1.f;
            #pragma unroll
            for (int mi = 0; mi < 4; ++mi) {
                #pragma unroll
                for (int ni = 0; ni < 2; ++ni) {
                    int d = ni*16 + l15;
                    #pragma unroll
                    for (int r = 0; r < 4; ++r) {
                        int pt = tm + mi*16 + l4*4 + r;
                        int b = pt >> 10, p = pt & 1023;
                        float s = sint[p*32 + d], cc = cost[p*32 + d];
                        float t0 = acc[mi][ni][r], t1 = acc[mi][ni+2][r];
                        size_t o = (size_t)(b*NHEAD + h)*HW*HD + (size_t)p*HD + d;
                        dst[o]      = f2bf((t0*cc - t1*s) * scale);
                        dst[o + 32] = f2bf((t1*cc + t0*s) * scale);
                    }
                }
            }
        } else {
            #pragma unroll
            for (int mi = 0; mi < 4; ++mi) {
                int pt = tm + mi*16 + l4*4;
                int b = pt >> 10, p = pt & 1023;
                size_t hb = (size_t)(b*NHEAD + h)*HD*HW;
                #pragma unroll
                for (int ni = 0; ni < 4; ++ni) {
                    int d = ni*16 + l15;
                    ushort4_t pk;
                    pk.x = f2bf(acc[mi][ni][0]);
                    pk.y = f2bf(acc[mi][ni][1]);
                    pk.z = f2bf(acc[mi][ni][2]);
                    pk.w = f2bf(acc[mi][ni][3]);
                    *(ushort4_t*)&VTt[hb + (size_t)d*HW + p] = pk;
                }
            }
        }
    } else {
        #pragma unroll
        for (int mi = 0; mi < 4; ++mi)
            #pragma unroll
            for (int ni = 0; ni < 4; ++ni)
                #pragma unroll
                for (int r = 0; r < 4; ++r) {
                    int row = tm + mi*16 + l4*4 + r;
                    int col = tn + ni*16 + l15;
                    C[(size_t)row*(64*NT) + col] = acc[mi][ni][r];
                }
    }
}

// ---------------- flash attention: LDS-staged K/V, double-buffered, swizzled ----------------
__global__ __launch_bounds__(256) void attn_kernel(const ushort_t* __restrict__ Q,
                                                   const ushort_t* __restrict__ Kt,
                                                   const ushort_t* __restrict__ VT,
                                                   ushort_t* __restrict__ Ao) {
    __shared__ ushort_t Kb[2][64*64];
    __shared__ ushort_t Vb[2][64*64];
    __shared__ ushort_t P[4][16][72];
    int flat = blockIdx.x;
    int swz = (flat & 7) * 96 + (flat >> 3);
    int bh = swz >> 4;
    int qtile = swz & 15;
    int w = threadIdx.x >> 6, lane = threadIdx.x & 63;
    int l15 = lane & 15, l4 = lane >> 4;
    int qbase = qtile * 64 + w * 16;
    int q = qbase + l15;
    int qr = q >> 5, qc = q & 31;
    const ushort_t* Qh = Q + (size_t)bh * HW * HD;
    const ushort_t* Kh = Kt + (size_t)bh * HW * HD;
    const ushort_t* Vh = VT + (size_t)bh * HD * HW;
    short8 aq0 = *(const short8*)&Qh[(size_t)q*64 + l4*8];
    short8 aq1 = *(const short8*)&Qh[(size_t)q*64 + 32 + l4*8];
    unsigned pat = (qc == 0) ? 3u : (7u << (qc - 1));
    float m = -1e30f, lsum = 0.f;
    f32x4 oacc[4] = {};

    auto stage = [&](int bufi, int kv) {
        #pragma unroll
        for (int is = 0; is < 2; ++is) {
            int c = is*256 + w*64 + lane;
            int row = c >> 3;
            int col16 = (c & 7) ^ (row & 7);
            const ushort_t* ga = Kh + (size_t)(kv + row)*64 + col16*8;
            __builtin_amdgcn_global_load_lds((const __attribute__((address_space(1))) void*)ga,
                (__attribute__((address_space(3))) void*)(&Kb[bufi][(size_t)(is*256 + w*64)*8]), 16, 0, 0);
            const ushort_t* gv = Vh + (size_t)row*HW + kv + col16*8;
            __builtin_amdgcn_global_load_lds((const __attribute__((address_space(1))) void*)gv,
                (__attribute__((address_space(3))) void*)(&Vb[bufi][(size_t)(is*256 + w*64)*8]), 16, 0, 0);
        }
    };

    int cur = 0;
    stage(0, 0);
    __syncthreads();

    for (int t = 0; t < 16; ++t) {
        int kv = t * 64;
        if (t < 15) stage(cur ^ 1, kv + 64);
        int sw = l15 & 7;
        f32x4 s[4];
        #pragma unroll
        for (int st = 0; st < 4; ++st) {
            int krow = st*16 + l15;
            short8 bk0 = *(const short8*)&Kb[cur][(size_t)krow*64 + (size_t)((l4 ^ sw))*8];
            short8 bk1 = *(const short8*)&Kb[cur][(size_t)krow*64 + (size_t)(((4+l4) ^ sw))*8];
            f32x4 z = {};
            z = __builtin_amdgcn_mfma_f32_16x16x32_bf16(bk0, aq0, z, 0, 0, 0);
            z = __builtin_amdgcn_mfma_f32_16x16x32_bf16(bk1, aq1, z, 0, 0, 0);
            s[st] = z;
        }
        short8 va0[4], va1[4];
        #pragma unroll
        for (int dt = 0; dt < 4; ++dt) {
            int vrow = dt*16 + l15;
            va0[dt] = *(const short8*)&Vb[cur][(size_t)vrow*64 + (size_t)((l4 ^ sw))*8];
            va1[dt] = *(const short8*)&Vb[cur][(size_t)vrow*64 + (size_t)(((4+l4) ^ sw))*8];
        }
        int dr = qr - (kv >> 5);
        if (dr >= -1 && dr <= 2) {
            u64 tm = 0;
            if (dr <= 1) tm |= (u64)pat;
            if (dr >= 0) tm |= ((u64)pat) << 32;
            u64 sub = tm >> (l4*4);
            #pragma unroll
            for (int st = 0; st < 4; ++st)
                #pragma unroll
                for (int i = 0; i < 4; ++i)
                    if ((sub >> (st*16 + i)) & 1) s[st][i] = -1e30f;
        }
        float vmax = fmaxf(
            fmaxf(fmaxf(fmaxf(s[0][0], s[0][1]), fmaxf(s[0][2], s[0][3])),
                  fmaxf(fmaxf(s[1][0], s[1][1]), fmaxf(s[1][2], s[1][3]))),
            fmaxf(fmaxf(fmaxf(s[2][0], s[2][1]), fmaxf(s[2][2], s[2][3])),
                  fmaxf(fmaxf(s[3][0], s[3][1]), fmaxf(s[3][2], s[3][3]))));
        vmax = fmaxf(vmax, __shfl_xor(vmax, 16, 64));
        vmax = fmaxf(vmax, __shfl_xor(vmax, 32, 64));
        if (__any(vmax - m > 8.f)) {
            float mn = fmaxf(m, vmax);
            float sf = ex2(m - mn);
            lsum *= sf;
            #pragma unroll
            for (int dt = 0; dt < 4; ++dt)
                #pragma unroll
                for (int i = 0; i < 4; ++i) oacc[dt][i] *= sf;
            m = mn;
        }
        float ls = 0.f;
        #pragma unroll
        for (int st = 0; st < 4; ++st) {
            float p0 = ex2(s[st][0] - m), p1 = ex2(s[st][1] - m);
            float p2 = ex2(s[st][2] - m), p3 = ex2(s[st][3] - m);
            ls += (p0 + p1) + (p2 + p3);
            uint2 pk;
            pk.x = cvtpk(p0, p1);
            pk.y = cvtpk(p2, p3);
            *(uint2*)&P[w][l15][st*16 + l4*4] = pk;
        }
        ls += __shfl_xor(ls, 16, 64);
        ls += __shfl_xor(ls, 32, 64);
        lsum += ls;
        short8 pf0 = *(const short8*)&P[w][l15][l4*8];
        short8 pf1 = *(const short8*)&P[w][l15][32 + l4*8];
        #pragma unroll
        for (int dt = 0; dt < 4; ++dt) {
            oacc[dt] = __builtin_amdgcn_mfma_f32_16x16x32_bf16(va0[dt], pf0, oacc[dt], 0, 0, 0);
            oacc[dt] = __builtin_amdgcn_mfma_f32_16x16x32_bf16(va1[dt], pf1, oacc[dt], 0, 0, 0);
        }
        __syncthreads();
        cur ^= 1;
    }
    int b = bh / NHEAD, h = bh % NHEAD;
    float rl = 1.f / lsum;
    size_t obase = ((size_t)b*HW + q)*D_MODEL + h*64;
    #pragma unroll
    for (int dt = 0; dt < 4; ++dt) {
        uint2 pk;
        pk.x = cvtpk(oacc[dt][0]*rl, oacc[dt][1]*rl);
        pk.y = cvtpk(oacc[dt][2]*rl, oacc[dt][3]*rl);
        *(uint2*)&Ao[obase + dt*16 + l4*4] = pk;
    }
}

extern "C" void kernel_launch(void* const* d_in, const int* in_sizes, int n_in,
                              void* d_out, int out_size, void* d_ws, size_t ws_size,
                              hipStream_t stream) {
    const float* x      = (const float*)d_in[0];
    const float* w_qkv  = (const float*)d_in[1];
    const float* w_out  = (const float*)d_in[2];
    const float* gamma  = (const float*)d_in[3];
    float* out = (float*)d_out;

    char* ws = (char*)d_ws;
    size_t off = 0;
    auto alloc = [&](size_t bytes) { char* p = ws + off; off += (bytes + 255) & ~255ull; return p; };
    ushort_t* xn   = (ushort_t*)alloc((size_t)TOK*D_MODEL*2);
    ushort_t* wq   = (ushort_t*)alloc((size_t)QKV_N*D_MODEL*2);
    ushort_t* wo   = (ushort_t*)alloc((size_t)D_MODEL*D_MODEL*2);
    float* sint    = (float*)alloc((size_t)HW*32*4);
    float* cost    = (float*)alloc((size_t)HW*32*4);
    ushort_t* Qr   = (ushort_t*)alloc((size_t)BH*HW*HD*2);
    ushort_t* Kr   = (ushort_t*)alloc((size_t)BH*HW*HD*2);
    ushort_t* VTt  = (ushort_t*)alloc((size_t)BH*HD*HW*2);
    ushort_t* Ao   = (ushort_t*)alloc((size_t)TOK*D_MODEL*2);

    rmsnorm_kernel<<<TOK/4, 256, 0, stream>>>(x, gamma, xn);
    cvt_kernel<<<(QKV_N*D_MODEL + 255)/256, 256, 0, stream>>>(w_qkv, wq, QKV_N*D_MODEL);
    cvt_kernel<<<(D_MODEL*D_MODEL + 255)/256, 256, 0, stream>>>(w_out, wo, D_MODEL*D_MODEL);
    sincos_kernel<<<HW*32/256, 256, 0, stream>>>(sint, cost);
    gemm64<36,0><<<2304, 64, 0, stream>>>(xn, wq, sint, cost, Qr, Kr, VTt, nullptr);
    attn_kernel<<<768, 256, 0, stream>>>(Qr, Kr, VTt, Ao);
    gemm64<12,1><<<768, 64, 0, stream>>>(Ao, wo, nullptr, nullptr, nullptr, nullptr, nullptr, out);
}

// Round 9
// 86.574 us; speedup vs baseline: 1.2820x; 1.2820x over previous
//
#include <hip/hip_runtime.h>

typedef __attribute__((ext_vector_type(8))) short short8;
typedef __attribute__((ext_vector_type(4))) float f32x4;
typedef __attribute__((ext_vector_type(4))) unsigned short ushort4_t;
typedef unsigned short ushort_t;
typedef unsigned long long u64;

#define D_MODEL 768
#define NHEAD 12
#define HD 64
#define BATCH 4
#define HWIDTH 32
#define HW 1024
#define TOK (BATCH*HW)
#define QKV_N (3*D_MODEL)
#define BH (BATCH*NHEAD)
#define QSCALE 0.18033688f  /* 0.125 * log2(e) */

__device__ __forceinline__ ushort_t f2bf(float f) {
    union { float f; unsigned u; } v; v.f = f;
    unsigned u = v.u;
    unsigned r = u + 0x7FFFu + ((u >> 16) & 1u);
    return (ushort_t)(r >> 16);
}
__device__ __forceinline__ float bf2f(ushort_t h) {
    union { unsigned u; float f; } v; v.u = ((unsigned)h) << 16;
    return v.f;
}
__device__ __forceinline__ float ex2(float x) {
    float r; asm("v_exp_f32 %0, %1" : "=v"(r) : "v"(x)); return r;
}
__device__ __forceinline__ unsigned cvtpk(float lo, float hi) {
    unsigned r; asm("v_cvt_pk_bf16_f32 %0, %1, %2" : "=v"(r) : "v"(lo), "v"(hi)); return r;
}

// ---------------- RMSNorm: one wave per token ----------------
__global__ void rmsnorm_kernel(const float* __restrict__ x, const float* __restrict__ gamma,
                               ushort_t* __restrict__ xn) {
    int wave = threadIdx.x >> 6, lane = threadIdx.x & 63;
    int t = blockIdx.x * 4 + wave;
    const float* xr = x + (size_t)t * D_MODEL;
    float v[12]; float ss = 0.f;
    #pragma unroll
    for (int j = 0; j < 12; ++j) { v[j] = xr[lane + j*64]; ss += v[j]*v[j]; }
    #pragma unroll
    for (int m = 1; m < 64; m <<= 1) ss += __shfl_xor(ss, m, 64);
    float r = rsqrtf(ss * (1.f/768.f) + 1e-6f);
    ushort_t* o = xn + (size_t)t * D_MODEL;
    #pragma unroll
    for (int j = 0; j < 12; ++j) o[lane + j*64] = f2bf(v[j] * r * gamma[lane + j*64]);
}

// ---------------- f32 -> bf16 convert ----------------
__global__ void cvt_kernel(const float* __restrict__ in, ushort_t* __restrict__ out, int n) {
    int i = blockIdx.x * blockDim.x + threadIdx.x;
    if (i < n) out[i] = f2bf(in[i]);
}

// ---------------- axial RoPE sin/cos tables (1024 x 32) ----------------
__global__ void sincos_kernel(float* __restrict__ sint, float* __restrict__ cost) {
    int i = blockIdx.x * blockDim.x + threadIdx.x; // 32768
    int p = i >> 5, j = i & 31;
    int r = p >> 5, c = p & 31;
    int jj = j & 15;
    float freq = powf(10000.f, -(float)(2*jj) / 32.f);
    float pos = (j < 16) ? (float)r : (float)c;
    float th = pos * freq;
    sint[i] = sinf(th);
    cost[i] = cosf(th);
}

// ---------------- 128x128 GEMM, BK=64, 4 buffers, counted-vmcnt, 1 raw barrier/step ----------------
// C[4096, 128*NTILES] = A[4096,768] * B[.,768]^T.  EPI: 0 = fused RoPE/V epilogue, 1 = f32 C.
template<int NTILES, int EPI>
__global__ __launch_bounds__(256, 1) void gemm128(const ushort_t* __restrict__ A,
                                                  const ushort_t* __restrict__ B,
                                                  const float* __restrict__ sint,
                                                  const float* __restrict__ cost,
                                                  ushort_t* __restrict__ Qr,
                                                  ushort_t* __restrict__ Kr,
                                                  ushort_t* __restrict__ VTt,
                                                  float* __restrict__ C) {
    __shared__ ushort_t As[4][128*64];   // 64 KB
    __shared__ ushort_t Bs[4][128*64];   // 64 KB
    const int K = 768;
    constexpr int NR = NTILES / 2;       // ntiles per chunk
    // 2-D XCD chunking: chunk c -> 8 mtiles x NR ntiles (A 1.5MB + B <=1.7MB per L2)
    int c = blockIdx.x & 7;
    int l = blockIdx.x >> 3;
    int mtile = (c >> 1)*8 + l / NR;
    int ntile = (c & 1)*NR + l % NR;
    int tm = mtile * 128, tn = ntile * 128;
    int w = threadIdx.x >> 6, lane = threadIdx.x & 63;
    int wr = w >> 1, wc = w & 1;
    int l15 = lane & 15, l4 = lane >> 4;

    // staging: waves 0,1 -> A rows, waves 2,3 -> B rows; 8 instrs/wave, each 8 rows x 128B.
    // global source slot pre-swizzled: LDS[row][s] = G[row][s ^ (row&7)]
    const ushort_t* mat = (w < 2) ? A : B;
    int mbase = (w < 2) ? tm : tn;
    ushort_t* lds_half = (w < 2) ? &As[0][0] : &Bs[0][0];
    int r0w = (w & 1) * 64;                      // wave's 64-row half
    int srow = r0w + (lane >> 3);                // + j*8
    int sslot = (lane & 7) ^ (srow & 7);
    const ushort_t* gsrc0 = mat + (size_t)(mbase + srow)*K + sslot*8;

    auto stage = [&](int buf, int kstep) {
        int k0 = kstep * 64;
        #pragma unroll
        for (int j = 0; j < 8; ++j) {
            const ushort_t* g = gsrc0 + (size_t)(j*8)*K + k0;
            __builtin_amdgcn_global_load_lds((const __attribute__((address_space(1))) void*)g,
                (__attribute__((address_space(3))) void*)(lds_half + (size_t)buf*8192 + (r0w + j*8)*64),
                16, 0, 0);
        }
    };

    f32x4 acc[4][4] = {};
    auto compute = [&](int bi) {
        short8 af[4][2], bfx[4][2];
        #pragma unroll
        for (int mi = 0; mi < 4; ++mi) {
            int row = wr*64 + mi*16 + l15;
            #pragma unroll
            for (int kk = 0; kk < 2; ++kk)
                af[mi][kk] = *(const short8*)&As[bi][row*64 + ((kk*4 + l4) ^ (row & 7))*8];
        }
        #pragma unroll
        for (int ni = 0; ni < 4; ++ni) {
            int row = wc*64 + ni*16 + l15;
            #pragma unroll
            for (int kk = 0; kk < 2; ++kk)
                bfx[ni][kk] = *(const short8*)&Bs[bi][row*64 + ((kk*4 + l4) ^ (row & 7))*8];
        }
        #pragma unroll
        for (int kk = 0; kk < 2; ++kk)
            #pragma unroll
            for (int mi = 0; mi < 4; ++mi)
                #pragma unroll
                for (int ni = 0; ni < 4; ++ni)
                    acc[mi][ni] = __builtin_amdgcn_mfma_f32_16x16x32_bf16(af[mi][kk], bfx[ni][kk], acc[mi][ni], 0, 0, 0);
    };

    stage(0, 0); stage(1, 1);
    #pragma unroll
    for (int t = 0; t < 10; ++t) {
        stage((t + 2) & 3, t + 2);
        asm volatile("s_waitcnt vmcnt(16)" ::: "memory");
        __builtin_amdgcn_s_barrier();
        compute(t & 3);
    }
    asm volatile("s_waitcnt vmcnt(8)" ::: "memory");
    __builtin_amdgcn_s_barrier();
    compute(2);
    asm volatile("s_waitcnt vmcnt(0)" ::: "memory");
    __builtin_amdgcn_s_barrier();
    compute(3);

    if constexpr (EPI == 0) {
        int col_base = tn + wc*64;           // 64-aligned -> one head, one region
        int region = col_base / 768;         // 0=Q 1=K 2=V
        int h = (col_base % 768) >> 6;
        if (region < 2) {
            ushort_t* dst = (region == 0) ? Qr : Kr;
            float scale = (region == 0) ? QSCALE : 1.f;
            #pragma unroll
            for (int mi = 0; mi < 4; ++mi) {
                #pragma unroll
                for (int ni = 0; ni < 2; ++ni) {
                    int d = ni*16 + l15;
                    #pragma unroll
                    for (int r = 0; r < 4; ++r) {
                        int pt = tm + wr*64 + mi*16 + l4*4 + r;
                        int b = pt >> 10, p = pt & 1023;
                        float s = sint[p*32 + d], cc = cost[p*32 + d];
                        float t0 = acc[mi][ni][r], t1 = acc[mi][ni+2][r];
                        size_t o = (size_t)(b*NHEAD + h)*HW*HD + (size_t)p*HD + d;
                        dst[o]      = f2bf((t0*cc - t1*s) * scale);
                        dst[o + 32] = f2bf((t1*cc + t0*s) * scale);
                    }
                }
            }
        } else {
            #pragma unroll
            for (int mi = 0; mi < 4; ++mi) {
                int pt = tm + wr*64 + mi*16 + l4*4;
                int b = pt >> 10, p = pt & 1023;
                size_t hb = (size_t)(b*NHEAD + h)*HD*HW;
                #pragma unroll
                for (int ni = 0; ni < 4; ++ni) {
                    int d = ni*16 + l15;
                    ushort4_t pk;
                    pk.x = f2bf(acc[mi][ni][0]);
                    pk.y = f2bf(acc[mi][ni][1]);
                    pk.z = f2bf(acc[mi][ni][2]);
                    pk.w = f2bf(acc[mi][ni][3]);
                    *(ushort4_t*)&VTt[hb + (size_t)d*HW + p] = pk;
                }
            }
        }
    } else {
        #pragma unroll
        for (int mi = 0; mi < 4; ++mi)
            #pragma unroll
            for (int ni = 0; ni < 4; ++ni)
                #pragma unroll
                for (int r = 0; r < 4; ++r) {
                    int row = tm + wr*64 + mi*16 + l4*4 + r;
                    int col = tn + wc*64 + ni*16 + l15;
                    C[(size_t)row*(128*NTILES) + col] = acc[mi][ni][r];
                }
    }
}

// ---------------- flash attention: LDS-staged K/V, double-buffered, swizzled ----------------
__global__ __launch_bounds__(256) void attn_kernel(const ushort_t* __restrict__ Q,
                                                   const ushort_t* __restrict__ Kt,
                                                   const ushort_t* __restrict__ VT,
                                                   ushort_t* __restrict__ Ao) {
    __shared__ ushort_t Kb[2][64*64];
    __shared__ ushort_t Vb[2][64*64];
    __shared__ ushort_t P[4][16][72];
    int flat = blockIdx.x;
    int swz = (flat & 7) * 96 + (flat >> 3);
    int bh = swz >> 4;
    int qtile = swz & 15;
    int w = threadIdx.x >> 6, lane = threadIdx.x & 63;
    int l15 = lane & 15, l4 = lane >> 4;
    int qbase = qtile * 64 + w * 16;
    int q = qbase + l15;
    int qr = q >> 5, qc = q & 31;
    const ushort_t* Qh = Q + (size_t)bh * HW * HD;
    const ushort_t* Kh = Kt + (size_t)bh * HW * HD;
    const ushort_t* Vh = VT + (size_t)bh * HD * HW;
    short8 aq0 = *(const short8*)&Qh[(size_t)q*64 + l4*8];
    short8 aq1 = *(const short8*)&Qh[(size_t)q*64 + 32 + l4*8];
    unsigned pat = (qc == 0) ? 3u : (7u << (qc - 1));
    float m = -1e30f, lsum = 0.f;
    f32x4 oacc[4] = {};

    auto stage = [&](int bufi, int kv) {
        #pragma unroll
        for (int is = 0; is < 2; ++is) {
            int c = is*256 + w*64 + lane;
            int row = c >> 3;
            int col16 = (c & 7) ^ (row & 7);
            const ushort_t* ga = Kh + (size_t)(kv + row)*64 + col16*8;
            __builtin_amdgcn_global_load_lds((const __attribute__((address_space(1))) void*)ga,
                (__attribute__((address_space(3))) void*)(&Kb[bufi][(size_t)(is*256 + w*64)*8]), 16, 0, 0);
            const ushort_t* gv = Vh + (size_t)row*HW + kv + col16*8;
            __builtin_amdgcn_global_load_lds((const __attribute__((address_space(1))) void*)gv,
                (__attribute__((address_space(3))) void*)(&Vb[bufi][(size_t)(is*256 + w*64)*8]), 16, 0, 0);
        }
    };

    int cur = 0;
    stage(0, 0);
    __syncthreads();

    for (int t = 0; t < 16; ++t) {
        int kv = t * 64;
        if (t < 15) stage(cur ^ 1, kv + 64);
        int sw = l15 & 7;
        f32x4 s[4];
        #pragma unroll
        for (int st = 0; st < 4; ++st) {
            int krow = st*16 + l15;
            short8 bk0 = *(const short8*)&Kb[cur][(size_t)krow*64 + (size_t)((l4 ^ sw))*8];
            short8 bk1 = *(const short8*)&Kb[cur][(size_t)krow*64 + (size_t)(((4+l4) ^ sw))*8];
            f32x4 z = {};
            z = __builtin_amdgcn_mfma_f32_16x16x32_bf16(bk0, aq0, z, 0, 0, 0);
            z = __builtin_amdgcn_mfma_f32_16x16x32_bf16(bk1, aq1, z, 0, 0, 0);
            s[st] = z;
        }
        short8 va0[4], va1[4];
        #pragma unroll
        for (int dt = 0; dt < 4; ++dt) {
            int vrow = dt*16 + l15;
            va0[dt] = *(const short8*)&Vb[cur][(size_t)vrow*64 + (size_t)((l4 ^ sw))*8];
            va1[dt] = *(const short8*)&Vb[cur][(size_t)vrow*64 + (size_t)(((4+l4) ^ sw))*8];
        }
        int dr = qr - (kv >> 5);
        if (dr >= -1 && dr <= 2) {
            u64 tm = 0;
            if (dr <= 1) tm |= (u64)pat;
            if (dr >= 0) tm |= ((u64)pat) << 32;
            u64 sub = tm >> (l4*4);
            #pragma unroll
            for (int st = 0; st < 4; ++st)
                #pragma unroll
                for (int i = 0; i < 4; ++i)
                    if ((sub >> (st*16 + i)) & 1) s[st][i] = -1e30f;
        }
        float vmax = fmaxf(
            fmaxf(fmaxf(fmaxf(s[0][0], s[0][1]), fmaxf(s[0][2], s[0][3])),
                  fmaxf(fmaxf(s[1][0], s[1][1]), fmaxf(s[1][2], s[1][3]))),
            fmaxf(fmaxf(fmaxf(s[2][0], s[2][1]), fmaxf(s[2][2], s[2][3])),
                  fmaxf(fmaxf(s[3][0], s[3][1]), fmaxf(s[3][2], s[3][3]))));
        vmax = fmaxf(vmax, __shfl_xor(vmax, 16, 64));
        vmax = fmaxf(vmax, __shfl_xor(vmax, 32, 64));
        if (__any(vmax - m > 8.f)) {
            float mn = fmaxf(m, vmax);
            float sf = ex2(m - mn);
            lsum *= sf;
            #pragma unroll
            for (int dt = 0; dt < 4; ++dt)
                #pragma unroll
                for (int i = 0; i < 4; ++i) oacc[dt][i] *= sf;
            m = mn;
        }
        float ls = 0.f;
        #pragma unroll
        for (int st = 0; st < 4; ++st) {
            float p0 = ex2(s[st][0] - m), p1 = ex2(s[st][1] - m);
            float p2 = ex2(s[st][2] - m), p3 = ex2(s[st][3] - m);
            ls += (p0 + p1) + (p2 + p3);
            uint2 pk;
            pk.x = cvtpk(p0, p1);
            pk.y = cvtpk(p2, p3);
            *(uint2*)&P[w][l15][st*16 + l4*4] = pk;
        }
        ls += __shfl_xor(ls, 16, 64);
        ls += __shfl_xor(ls, 32, 64);
        lsum += ls;
        short8 pf0 = *(const short8*)&P[w][l15][l4*8];
        short8 pf1 = *(const short8*)&P[w][l15][32 + l4*8];
        #pragma unroll
        for (int dt = 0; dt < 4; ++dt) {
            oacc[dt] = __builtin_amdgcn_mfma_f32_16x16x32_bf16(va0[dt], pf0, oacc[dt], 0, 0, 0);
            oacc[dt] = __builtin_amdgcn_mfma_f32_16x16x32_bf16(va1[dt], pf1, oacc[dt], 0, 0, 0);
        }
        __syncthreads();
        cur ^= 1;
    }
    int b = bh / NHEAD, h = bh % NHEAD;
    float rl = 1.f / lsum;
    size_t obase = ((size_t)b*HW + q)*D_MODEL + h*64;
    #pragma unroll
    for (int dt = 0; dt < 4; ++dt) {
        uint2 pk;
        pk.x = cvtpk(oacc[dt][0]*rl, oacc[dt][1]*rl);
        pk.y = cvtpk(oacc[dt][2]*rl, oacc[dt][3]*rl);
        *(uint2*)&Ao[obase + dt*16 + l4*4] = pk;
    }
}

extern "C" void kernel_launch(void* const* d_in, const int* in_sizes, int n_in,
                              void* d_out, int out_size, void* d_ws, size_t ws_size,
                              hipStream_t stream) {
    const float* x      = (const float*)d_in[0];
    const float* w_qkv  = (const float*)d_in[1];
    const float* w_out  = (const float*)d_in[2];
    const float* gamma  = (const float*)d_in[3];
    float* out = (float*)d_out;

    char* ws = (char*)d_ws;
    size_t off = 0;
    auto alloc = [&](size_t bytes) { char* p = ws + off; off += (bytes + 255) & ~255ull; return p; };
    ushort_t* xn   = (ushort_t*)alloc((size_t)TOK*D_MODEL*2);
    ushort_t* wq   = (ushort_t*)alloc((size_t)QKV_N*D_MODEL*2);
    ushort_t* wo   = (ushort_t*)alloc((size_t)D_MODEL*D_MODEL*2);
    float* sint    = (float*)alloc((size_t)HW*32*4);
    float* cost    = (float*)alloc((size_t)HW*32*4);
    ushort_t* Qr   = (ushort_t*)alloc((size_t)BH*HW*HD*2);
    ushort_t* Kr   = (ushort_t*)alloc((size_t)BH*HW*HD*2);
    ushort_t* VTt  = (ushort_t*)alloc((size_t)BH*HD*HW*2);
    ushort_t* Ao   = (ushort_t*)alloc((size_t)TOK*D_MODEL*2);

    rmsnorm_kernel<<<TOK/4, 256, 0, stream>>>(x, gamma, xn);
    cvt_kernel<<<(QKV_N*D_MODEL + 255)/256, 256, 0, stream>>>(w_qkv, wq, QKV_N*D_MODEL);
    cvt_kernel<<<(D_MODEL*D_MODEL + 255)/256, 256, 0, stream>>>(w_out, wo, D_MODEL*D_MODEL);
    sincos_kernel<<<HW*32/256, 256, 0, stream>>>(sint, cost);
    gemm128<18,0><<<576, 256, 0, stream>>>(xn, wq, sint, cost, Qr, Kr, VTt, nullptr);
    attn_kernel<<<768, 256, 0, stream>>>(Qr, Kr, VTt, Ao);
    gemm128<6,1><<<192, 256, 0, stream>>>(Ao, wo, nullptr, nullptr, nullptr, nullptr, nullptr, out);
}

// Round 10
// 80.102 us; speedup vs baseline: 1.3856x; 1.0808x over previous
//
#include <hip/hip_runtime.h>

typedef __attribute__((ext_vector_type(8))) short short8;
typedef __attribute__((ext_vector_type(4))) float f32x4;
typedef __attribute__((ext_vector_type(4))) unsigned short ushort4_t;
typedef unsigned short ushort_t;
typedef unsigned long long u64;

#define D_MODEL 768
#define NHEAD 12
#define HD 64
#define BATCH 4
#define HWIDTH 32
#define HW 1024
#define TOK (BATCH*HW)
#define QKV_N (3*D_MODEL)
#define BH (BATCH*NHEAD)
#define QSCALE 0.18033688f  /* 0.125 * log2(e) */

__device__ __forceinline__ ushort_t f2bf(float f) {
    union { float f; unsigned u; } v; v.f = f;
    unsigned u = v.u;
    unsigned r = u + 0x7FFFu + ((u >> 16) & 1u);
    return (ushort_t)(r >> 16);
}
__device__ __forceinline__ float bf2f(ushort_t h) {
    union { unsigned u; float f; } v; v.u = ((unsigned)h) << 16;
    return v.f;
}
__device__ __forceinline__ float ex2(float x) {
    float r; asm("v_exp_f32 %0, %1" : "=v"(r) : "v"(x)); return r;
}
__device__ __forceinline__ unsigned cvtpk(float lo, float hi) {
    unsigned r; asm("v_cvt_pk_bf16_f32 %0, %1, %2" : "=v"(r) : "v"(lo), "v"(hi)); return r;
}

// ---------------- RMSNorm: one wave per token ----------------
__global__ void rmsnorm_kernel(const float* __restrict__ x, const float* __restrict__ gamma,
                               ushort_t* __restrict__ xn) {
    int wave = threadIdx.x >> 6, lane = threadIdx.x & 63;
    int t = blockIdx.x * 4 + wave;
    const float* xr = x + (size_t)t * D_MODEL;
    float v[12]; float ss = 0.f;
    #pragma unroll
    for (int j = 0; j < 12; ++j) { v[j] = xr[lane + j*64]; ss += v[j]*v[j]; }
    #pragma unroll
    for (int m = 1; m < 64; m <<= 1) ss += __shfl_xor(ss, m, 64);
    float r = rsqrtf(ss * (1.f/768.f) + 1e-6f);
    ushort_t* o = xn + (size_t)t * D_MODEL;
    #pragma unroll
    for (int j = 0; j < 12; ++j) o[lane + j*64] = f2bf(v[j] * r * gamma[lane + j*64]);
}

// ---------------- f32 -> bf16 convert ----------------
__global__ void cvt_kernel(const float* __restrict__ in, ushort_t* __restrict__ out, int n) {
    int i = blockIdx.x * blockDim.x + threadIdx.x;
    if (i < n) out[i] = f2bf(in[i]);
}

// ---------------- axial RoPE sin/cos tables (1024 x 32) ----------------
__global__ void sincos_kernel(float* __restrict__ sint, float* __restrict__ cost) {
    int i = blockIdx.x * blockDim.x + threadIdx.x; // 32768
    int p = i >> 5, j = i & 31;
    int r = p >> 5, c = p & 31;
    int jj = j & 15;
    float freq = powf(10000.f, -(float)(2*jj) / 32.f);
    float pos = (j < 16) ? (float)r : (float)c;
    float th = pos * freq;
    sint[i] = sinf(th);
    cost[i] = cosf(th);
}

// ---------------- 128x128 GEMM, BK=64, 2 buffers, counted-vmcnt, 2 barriers/step ----------------
// C[4096, 128*NTILES] = A[4096,768] * B[.,768]^T.  EPI: 0 = fused RoPE/V epilogue, 1 = f32 C.
template<int NTILES, int EPI>
__global__ __launch_bounds__(256, 2) void gemm128(const ushort_t* __restrict__ A,
                                                  const ushort_t* __restrict__ B,
                                                  const float* __restrict__ sint,
                                                  const float* __restrict__ cost,
                                                  ushort_t* __restrict__ Qr,
                                                  ushort_t* __restrict__ Kr,
                                                  ushort_t* __restrict__ VTt,
                                                  float* __restrict__ C) {
    __shared__ ushort_t As[2][128*64];   // 32 KB
    __shared__ ushort_t Bs[2][128*64];   // 32 KB
    const int K = 768;
    constexpr int NR = NTILES / 2;       // ntiles per chunk
    // 2-D XCD chunking: chunk c -> 8 mtiles x NR ntiles (A 1.5MB + B <=1.7MB per L2)
    int c = blockIdx.x & 7;
    int l = blockIdx.x >> 3;
    int mtile = (c >> 1)*8 + l / NR;
    int ntile = (c & 1)*NR + l % NR;
    int tm = mtile * 128, tn = ntile * 128;
    int w = threadIdx.x >> 6, lane = threadIdx.x & 63;
    int wr = w >> 1, wc = w & 1;
    int l15 = lane & 15, l4 = lane >> 4;

    // staging: waves 0,1 -> A rows, waves 2,3 -> B rows; 8 instrs/wave, each 8 rows x 128B.
    // global source slot pre-swizzled: LDS[row][s] = G[row][s ^ (row&7)]
    const ushort_t* mat = (w < 2) ? A : B;
    int mbase = (w < 2) ? tm : tn;
    ushort_t* lds_half = (w < 2) ? &As[0][0] : &Bs[0][0];
    int r0w = (w & 1) * 64;                      // wave's 64-row half
    int srow = r0w + (lane >> 3);                // + j*8
    int sslot = (lane & 7) ^ (srow & 7);
    const ushort_t* gsrc0 = mat + (size_t)(mbase + srow)*K + sslot*8;

    auto stage = [&](int buf, int kstep) {
        int k0 = kstep * 64;
        #pragma unroll
        for (int j = 0; j < 8; ++j) {
            const ushort_t* g = gsrc0 + (size_t)(j*8)*K + k0;
            __builtin_amdgcn_global_load_lds((const __attribute__((address_space(1))) void*)g,
                (__attribute__((address_space(3))) void*)(lds_half + (size_t)buf*8192 + (r0w + j*8)*64),
                16, 0, 0);
        }
    };

    f32x4 acc[4][4] = {};
    auto compute = [&](int bi) {
        short8 af[4][2], bfx[4][2];
        #pragma unroll
        for (int mi = 0; mi < 4; ++mi) {
            int row = wr*64 + mi*16 + l15;
            #pragma unroll
            for (int kk = 0; kk < 2; ++kk)
                af[mi][kk] = *(const short8*)&As[bi][row*64 + ((kk*4 + l4) ^ (row & 7))*8];
        }
        #pragma unroll
        for (int ni = 0; ni < 4; ++ni) {
            int row = wc*64 + ni*16 + l15;
            #pragma unroll
            for (int kk = 0; kk < 2; ++kk)
                bfx[ni][kk] = *(const short8*)&Bs[bi][row*64 + ((kk*4 + l4) ^ (row & 7))*8];
        }
        #pragma unroll
        for (int kk = 0; kk < 2; ++kk)
            #pragma unroll
            for (int mi = 0; mi < 4; ++mi)
                #pragma unroll
                for (int ni = 0; ni < 4; ++ni)
                    acc[mi][ni] = __builtin_amdgcn_mfma_f32_16x16x32_bf16(af[mi][kk], bfx[ni][kk], acc[mi][ni], 0, 0, 0);
    };

    stage(0, 0); stage(1, 1);
    for (int t = 0; t < 12; ++t) {
        if (t < 11) { asm volatile("s_waitcnt vmcnt(8)" ::: "memory"); }
        else        { asm volatile("s_waitcnt vmcnt(0)" ::: "memory"); }
        __builtin_amdgcn_s_barrier();     // all waves' stage-t loads have landed
        compute(t & 1);
        __builtin_amdgcn_s_barrier();     // all waves done reading buf t&1
        if (t < 10) stage(t & 1, t + 2);  // recycle the buffer just read
    }

    if constexpr (EPI == 0) {
        int col_base = tn + wc*64;           // 64-aligned -> one head, one region
        int region = col_base / 768;         // 0=Q 1=K 2=V
        int h = (col_base % 768) >> 6;
        if (region < 2) {
            ushort_t* dst = (region == 0) ? Qr : Kr;
            float scale = (region == 0) ? QSCALE : 1.f;
            #pragma unroll
            for (int mi = 0; mi < 4; ++mi) {
                #pragma unroll
                for (int ni = 0; ni < 2; ++ni) {
                    int d = ni*16 + l15;
                    #pragma unroll
                    for (int r = 0; r < 4; ++r) {
                        int pt = tm + wr*64 + mi*16 + l4*4 + r;
                        int b = pt >> 10, p = pt & 1023;
                        float s = sint[p*32 + d], cc = cost[p*32 + d];
                        float t0 = acc[mi][ni][r], t1 = acc[mi][ni+2][r];
                        size_t o = (size_t)(b*NHEAD + h)*HW*HD + (size_t)p*HD + d;
                        dst[o]      = f2bf((t0*cc - t1*s) * scale);
                        dst[o + 32] = f2bf((t1*cc + t0*s) * scale);
                    }
                }
            }
        } else {
            #pragma unroll
            for (int mi = 0; mi < 4; ++mi) {
                int pt = tm + wr*64 + mi*16 + l4*4;
                int b = pt >> 10, p = pt & 1023;
                size_t hb = (size_t)(b*NHEAD + h)*HD*HW;
                #pragma unroll
                for (int ni = 0; ni < 4; ++ni) {
                    int d = ni*16 + l15;
                    ushort4_t pk;
                    pk.x = f2bf(acc[mi][ni][0]);
                    pk.y = f2bf(acc[mi][ni][1]);
                    pk.z = f2bf(acc[mi][ni][2]);
                    pk.w = f2bf(acc[mi][ni][3]);
                    *(ushort4_t*)&VTt[hb + (size_t)d*HW + p] = pk;
                }
            }
        }
    } else {
        #pragma unroll
        for (int mi = 0; mi < 4; ++mi)
            #pragma unroll
            for (int ni = 0; ni < 4; ++ni)
                #pragma unroll
                for (int r = 0; r < 4; ++r) {
                    int row = tm + wr*64 + mi*16 + l4*4 + r;
                    int col = tn + wc*64 + ni*16 + l15;
                    C[(size_t)row*(128*NTILES) + col] = acc[mi][ni][r];
                }
    }
}

// ---------------- flash attention: 2-buffer counted-vmcnt pipeline, swizzled LDS ----------------
__global__ __launch_bounds__(256) void attn_kernel(const ushort_t* __restrict__ Q,
                                                   const ushort_t* __restrict__ Kt,
                                                   const ushort_t* __restrict__ VT,
                                                   ushort_t* __restrict__ Ao) {
    __shared__ ushort_t Kb[2][64*64];
    __shared__ ushort_t Vb[2][64*64];
    __shared__ ushort_t P[4][16][72];
    int flat = blockIdx.x;
    int swz = (flat & 7) * 96 + (flat >> 3);
    int bh = swz >> 4;
    int qtile = swz & 15;
    int w = threadIdx.x >> 6, lane = threadIdx.x & 63;
    int l15 = lane & 15, l4 = lane >> 4;
    int qbase = qtile * 64 + w * 16;
    int q = qbase + l15;
    int qr = q >> 5, qc = q & 31;
    const ushort_t* Qh = Q + (size_t)bh * HW * HD;
    const ushort_t* Kh = Kt + (size_t)bh * HW * HD;
    const ushort_t* Vh = VT + (size_t)bh * HD * HW;
    short8 aq0 = *(const short8*)&Qh[(size_t)q*64 + l4*8];
    short8 aq1 = *(const short8*)&Qh[(size_t)q*64 + 32 + l4*8];
    unsigned pat = (qc == 0) ? 3u : (7u << (qc - 1));
    float m = -1e30f, lsum = 0.f;
    f32x4 oacc[4] = {};

    // per-wave stage = 4 loads (2 K + 2 V)
    auto stage = [&](int bufi, int kv) {
        #pragma unroll
        for (int is = 0; is < 2; ++is) {
            int c = is*256 + w*64 + lane;
            int row = c >> 3;
            int col16 = (c & 7) ^ (row & 7);
            const ushort_t* ga = Kh + (size_t)(kv + row)*64 + col16*8;
            __builtin_amdgcn_global_load_lds((const __attribute__((address_space(1))) void*)ga,
                (__attribute__((address_space(3))) void*)(&Kb[bufi][(size_t)(is*256 + w*64)*8]), 16, 0, 0);
            const ushort_t* gv = Vh + (size_t)row*HW + kv + col16*8;
            __builtin_amdgcn_global_load_lds((const __attribute__((address_space(1))) void*)gv,
                (__attribute__((address_space(3))) void*)(&Vb[bufi][(size_t)(is*256 + w*64)*8]), 16, 0, 0);
        }
    };

    stage(0, 0); stage(1, 64);

    for (int t = 0; t < 16; ++t) {
        if (t < 15) { asm volatile("s_waitcnt vmcnt(4)" ::: "memory"); }
        else        { asm volatile("s_waitcnt vmcnt(0)" ::: "memory"); }
        __builtin_amdgcn_s_barrier();     // all waves' stage-t loads landed
        int cur = t & 1;
        int kv = t * 64;
        int sw = l15 & 7;
        f32x4 s[4];
        #pragma unroll
        for (int st = 0; st < 4; ++st) {
            int krow = st*16 + l15;
            short8 bk0 = *(const short8*)&Kb[cur][(size_t)krow*64 + (size_t)((l4 ^ sw))*8];
            short8 bk1 = *(const short8*)&Kb[cur][(size_t)krow*64 + (size_t)(((4+l4) ^ sw))*8];
            f32x4 z = {};
            z = __builtin_amdgcn_mfma_f32_16x16x32_bf16(bk0, aq0, z, 0, 0, 0);
            z = __builtin_amdgcn_mfma_f32_16x16x32_bf16(bk1, aq1, z, 0, 0, 0);
            s[st] = z;
        }
        short8 va0[4], va1[4];
        #pragma unroll
        for (int dt = 0; dt < 4; ++dt) {
            int vrow = dt*16 + l15;
            va0[dt] = *(const short8*)&Vb[cur][(size_t)vrow*64 + (size_t)((l4 ^ sw))*8];
            va1[dt] = *(const short8*)&Vb[cur][(size_t)vrow*64 + (size_t)(((4+l4) ^ sw))*8];
        }
        int dr = qr - (kv >> 5);
        if (dr >= -1 && dr <= 2) {
            u64 tm = 0;
            if (dr <= 1) tm |= (u64)pat;
            if (dr >= 0) tm |= ((u64)pat) << 32;
            u64 sub = tm >> (l4*4);
            #pragma unroll
            for (int st = 0; st < 4; ++st)
                #pragma unroll
                for (int i = 0; i < 4; ++i)
                    if ((sub >> (st*16 + i)) & 1) s[st][i] = -1e30f;
        }
        float vmax = fmaxf(
            fmaxf(fmaxf(fmaxf(s[0][0], s[0][1]), fmaxf(s[0][2], s[0][3])),
                  fmaxf(fmaxf(s[1][0], s[1][1]), fmaxf(s[1][2], s[1][3]))),
            fmaxf(fmaxf(fmaxf(s[2][0], s[2][1]), fmaxf(s[2][2], s[2][3])),
                  fmaxf(fmaxf(s[3][0], s[3][1]), fmaxf(s[3][2], s[3][3]))));
        vmax = fmaxf(vmax, __shfl_xor(vmax, 16, 64));
        vmax = fmaxf(vmax, __shfl_xor(vmax, 32, 64));
        if (__any(vmax - m > 8.f)) {
            float mn = fmaxf(m, vmax);
            float sf = ex2(m - mn);
            lsum *= sf;
            #pragma unroll
            for (int dt = 0; dt < 4; ++dt)
                #pragma unroll
                for (int i = 0; i < 4; ++i) oacc[dt][i] *= sf;
            m = mn;
        }
        float ls = 0.f;
        #pragma unroll
        for (int st = 0; st < 4; ++st) {
            float p0 = ex2(s[st][0] - m), p1 = ex2(s[st][1] - m);
            float p2 = ex2(s[st][2] - m), p3 = ex2(s[st][3] - m);
            ls += (p0 + p1) + (p2 + p3);
            uint2 pk;
            pk.x = cvtpk(p0, p1);
            pk.y = cvtpk(p2, p3);
            *(uint2*)&P[w][l15][st*16 + l4*4] = pk;
        }
        ls += __shfl_xor(ls, 16, 64);
        ls += __shfl_xor(ls, 32, 64);
        lsum += ls;
        short8 pf0 = *(const short8*)&P[w][l15][l4*8];
        short8 pf1 = *(const short8*)&P[w][l15][32 + l4*8];
        #pragma unroll
        for (int dt = 0; dt < 4; ++dt) {
            oacc[dt] = __builtin_amdgcn_mfma_f32_16x16x32_bf16(va0[dt], pf0, oacc[dt], 0, 0, 0);
            oacc[dt] = __builtin_amdgcn_mfma_f32_16x16x32_bf16(va1[dt], pf1, oacc[dt], 0, 0, 0);
        }
        __builtin_amdgcn_s_barrier();     // all waves done reading buf cur
        if (t < 14) stage(cur, (t + 2) * 64);   // recycle buffer just read
    }
    int b = bh / NHEAD, h = bh % NHEAD;
    float rl = 1.f / lsum;
    size_t obase = ((size_t)b*HW + q)*D_MODEL + h*64;
    #pragma unroll
    for (int dt = 0; dt < 4; ++dt) {
        uint2 pk;
        pk.x = cvtpk(oacc[dt][0]*rl, oacc[dt][1]*rl);
        pk.y = cvtpk(oacc[dt][2]*rl, oacc[dt][3]*rl);
        *(uint2*)&Ao[obase + dt*16 + l4*4] = pk;
    }
}

extern "C" void kernel_launch(void* const* d_in, const int* in_sizes, int n_in,
                              void* d_out, int out_size, void* d_ws, size_t ws_size,
                              hipStream_t stream) {
    const float* x      = (const float*)d_in[0];
    const float* w_qkv  = (const float*)d_in[1];
    const float* w_out  = (const float*)d_in[2];
    const float* gamma  = (const float*)d_in[3];
    float* out = (float*)d_out;

    char* ws = (char*)d_ws;
    size_t off = 0;
    auto alloc = [&](size_t bytes) { char* p = ws + off; off += (bytes + 255) & ~255ull; return p; };
    ushort_t* xn   = (ushort_t*)alloc((size_t)TOK*D_MODEL*2);
    ushort_t* wq   = (ushort_t*)alloc((size_t)QKV_N*D_MODEL*2);
    ushort_t* wo   = (ushort_t*)alloc((size_t)D_MODEL*D_MODEL*2);
    float* sint    = (float*)alloc((size_t)HW*32*4);
    float* cost    = (float*)alloc((size_t)HW*32*4);
    ushort_t* Qr   = (ushort_t*)alloc((size_t)BH*HW*HD*2);
    ushort_t* Kr   = (ushort_t*)alloc((size_t)BH*HW*HD*2);
    ushort_t* VTt  = (ushort_t*)alloc((size_t)BH*HD*HW*2);
    ushort_t* Ao   = (ushort_t*)alloc((size_t)TOK*D_MODEL*2);

    rmsnorm_kernel<<<TOK/4, 256, 0, stream>>>(x, gamma, xn);
    cvt_kernel<<<(QKV_N*D_MODEL + 255)/256, 256, 0, stream>>>(w_qkv, wq, QKV_N*D_MODEL);
    cvt_kernel<<<(D_MODEL*D_MODEL + 255)/256, 256, 0, stream>>>(w_out, wo, D_MODEL*D_MODEL);
    sincos_kernel<<<HW*32/256, 256, 0, stream>>>(sint, cost);
    gemm128<18,0><<<576, 256, 0, stream>>>(xn, wq, sint, cost, Qr, Kr, VTt, nullptr);
    attn_kernel<<<768, 256, 0, stream>>>(Qr, Kr, VTt, Ao);
    gemm128<6,1><<<192, 256, 0, stream>>>(Ao, wo, nullptr, nullptr, nullptr, nullptr, nullptr, out);
}

// Round 11
// 77.507 us; speedup vs baseline: 1.4319x; 1.0335x over previous
//
#include <hip/hip_runtime.h>

typedef __attribute__((ext_vector_type(8))) short short8;
typedef __attribute__((ext_vector_type(4))) float f32x4;
typedef __attribute__((ext_vector_type(4))) unsigned short ushort4_t;
typedef unsigned short ushort_t;
typedef unsigned long long u64;

#define D_MODEL 768
#define NHEAD 12
#define HD 64
#define BATCH 4
#define HWIDTH 32
#define HW 1024
#define TOK (BATCH*HW)
#define QKV_N (3*D_MODEL)
#define BH (BATCH*NHEAD)
#define QSCALE 0.18033688f  /* 0.125 * log2(e) */

__device__ __forceinline__ ushort_t f2bf(float f) {
    union { float f; unsigned u; } v; v.f = f;
    unsigned u = v.u;
    unsigned r = u + 0x7FFFu + ((u >> 16) & 1u);
    return (ushort_t)(r >> 16);
}
__device__ __forceinline__ float ex2(float x) {
    float r; asm("v_exp_f32 %0, %1" : "=v"(r) : "v"(x)); return r;
}
__device__ __forceinline__ unsigned cvtpk(float lo, float hi) {
    unsigned r; asm("v_cvt_pk_bf16_f32 %0, %1, %2" : "=v"(r) : "v"(lo), "v"(hi)); return r;
}

// ---------------- fused prep: rmsnorm | cvt(w_qkv) | cvt(w_out) | sincos ----------------
// grid 3456: [0,1024) rmsnorm, [1024,2752) cvt wq, [2752,3328) cvt wo, [3328,3456) sincos
__global__ __launch_bounds__(256) void prep_kernel(const float* __restrict__ x,
                                                   const float* __restrict__ gamma,
                                                   ushort_t* __restrict__ xn,
                                                   const float* __restrict__ w_qkv,
                                                   ushort_t* __restrict__ wq,
                                                   const float* __restrict__ w_out,
                                                   ushort_t* __restrict__ wo,
                                                   float* __restrict__ sint,
                                                   float* __restrict__ cost) {
    int blk = blockIdx.x;
    if (blk < 1024) {
        int wave = threadIdx.x >> 6, lane = threadIdx.x & 63;
        int t = blk * 4 + wave;
        const float* xr = x + (size_t)t * D_MODEL;
        float v[12]; float ss = 0.f;
        #pragma unroll
        for (int j = 0; j < 12; ++j) { v[j] = xr[lane + j*64]; ss += v[j]*v[j]; }
        #pragma unroll
        for (int m = 1; m < 64; m <<= 1) ss += __shfl_xor(ss, m, 64);
        float r = rsqrtf(ss * (1.f/768.f) + 1e-6f);
        ushort_t* o = xn + (size_t)t * D_MODEL;
        #pragma unroll
        for (int j = 0; j < 12; ++j) o[lane + j*64] = f2bf(v[j] * r * gamma[lane + j*64]);
    } else if (blk < 2752) {
        int i = (blk - 1024) * 1024 + threadIdx.x * 4;
        float4 v = *(const float4*)&w_qkv[i];
        uint2 pk; pk.x = cvtpk(v.x, v.y); pk.y = cvtpk(v.z, v.w);
        *(uint2*)&wq[i] = pk;
    } else if (blk < 3328) {
        int i = (blk - 2752) * 1024 + threadIdx.x * 4;
        float4 v = *(const float4*)&w_out[i];
        uint2 pk; pk.x = cvtpk(v.x, v.y); pk.y = cvtpk(v.z, v.w);
        *(uint2*)&wo[i] = pk;
    } else {
        int i = (blk - 3328) * 256 + threadIdx.x;  // 0..32767
        int p = i >> 5, j = i & 31;
        int r = p >> 5, c = p & 31;
        int jj = j & 15;
        float freq = powf(10000.f, -(float)(2*jj) / 32.f);
        float pos = (j < 16) ? (float)r : (float)c;
        float th = pos * freq;
        sint[i] = sinf(th);
        cost[i] = cosf(th);
    }
}

// ---------------- 128x128 GEMM, BK=64, 2 buffers, counted-vmcnt, 2 barriers/step ----------------
template<int NTILES, int EPI>
__global__ __launch_bounds__(256, 2) void gemm128(const ushort_t* __restrict__ A,
                                                  const ushort_t* __restrict__ B,
                                                  const float* __restrict__ sint,
                                                  const float* __restrict__ cost,
                                                  ushort_t* __restrict__ Qr,
                                                  ushort_t* __restrict__ Kr,
                                                  ushort_t* __restrict__ VTt,
                                                  float* __restrict__ C) {
    __shared__ ushort_t As[2][128*64];
    __shared__ ushort_t Bs[2][128*64];
    const int K = 768;
    constexpr int NR = NTILES / 2;
    int c = blockIdx.x & 7;
    int l = blockIdx.x >> 3;
    int mtile = (c >> 1)*8 + l / NR;
    int ntile = (c & 1)*NR + l % NR;
    int tm = mtile * 128, tn = ntile * 128;
    int w = threadIdx.x >> 6, lane = threadIdx.x & 63;
    int wr = w >> 1, wc = w & 1;
    int l15 = lane & 15, l4 = lane >> 4;

    const ushort_t* mat = (w < 2) ? A : B;
    int mbase = (w < 2) ? tm : tn;
    ushort_t* lds_half = (w < 2) ? &As[0][0] : &Bs[0][0];
    int r0w = (w & 1) * 64;
    int srow = r0w + (lane >> 3);
    int sslot = (lane & 7) ^ (srow & 7);
    const ushort_t* gsrc0 = mat + (size_t)(mbase + srow)*K + sslot*8;

    auto stage = [&](int buf, int kstep) {
        int k0 = kstep * 64;
        #pragma unroll
        for (int j = 0; j < 8; ++j) {
            const ushort_t* g = gsrc0 + (size_t)(j*8)*K + k0;
            __builtin_amdgcn_global_load_lds((const __attribute__((address_space(1))) void*)g,
                (__attribute__((address_space(3))) void*)(lds_half + (size_t)buf*8192 + (r0w + j*8)*64),
                16, 0, 0);
        }
    };

    f32x4 acc[4][4] = {};
    auto compute = [&](int bi) {
        short8 af[4][2], bfx[4][2];
        #pragma unroll
        for (int mi = 0; mi < 4; ++mi) {
            int row = wr*64 + mi*16 + l15;
            #pragma unroll
            for (int kk = 0; kk < 2; ++kk)
                af[mi][kk] = *(const short8*)&As[bi][row*64 + ((kk*4 + l4) ^ (row & 7))*8];
        }
        #pragma unroll
        for (int ni = 0; ni < 4; ++ni) {
            int row = wc*64 + ni*16 + l15;
            #pragma unroll
            for (int kk = 0; kk < 2; ++kk)
                bfx[ni][kk] = *(const short8*)&Bs[bi][row*64 + ((kk*4 + l4) ^ (row & 7))*8];
        }
        #pragma unroll
        for (int kk = 0; kk < 2; ++kk)
            #pragma unroll
            for (int mi = 0; mi < 4; ++mi)
                #pragma unroll
                for (int ni = 0; ni < 4; ++ni)
                    acc[mi][ni] = __builtin_amdgcn_mfma_f32_16x16x32_bf16(af[mi][kk], bfx[ni][kk], acc[mi][ni], 0, 0, 0);
    };

    stage(0, 0); stage(1, 1);
    for (int t = 0; t < 12; ++t) {
        if (t < 11) { asm volatile("s_waitcnt vmcnt(8)" ::: "memory"); }
        else        { asm volatile("s_waitcnt vmcnt(0)" ::: "memory"); }
        __builtin_amdgcn_s_barrier();
        compute(t & 1);
        __builtin_amdgcn_s_barrier();
        if (t < 10) stage(t & 1, t + 2);
    }

    if constexpr (EPI == 0) {
        int col_base = tn + wc*64;
        int region = col_base / 768;
        int h = (col_base % 768) >> 6;
        if (region < 2) {
            ushort_t* dst = (region == 0) ? Qr : Kr;
            float scale = (region == 0) ? QSCALE : 1.f;
            #pragma unroll
            for (int mi = 0; mi < 4; ++mi) {
                #pragma unroll
                for (int ni = 0; ni < 2; ++ni) {
                    int d = ni*16 + l15;
                    #pragma unroll
                    for (int r = 0; r < 4; ++r) {
                        int pt = tm + wr*64 + mi*16 + l4*4 + r;
                        int b = pt >> 10, p = pt & 1023;
                        float s = sint[p*32 + d], cc = cost[p*32 + d];
                        float t0 = acc[mi][ni][r], t1 = acc[mi][ni+2][r];
                        size_t o = (size_t)(b*NHEAD + h)*HW*HD + (size_t)p*HD + d;
                        dst[o]      = f2bf((t0*cc - t1*s) * scale);
                        dst[o + 32] = f2bf((t1*cc + t0*s) * scale);
                    }
                }
            }
        } else {
            #pragma unroll
            for (int mi = 0; mi < 4; ++mi) {
                int pt = tm + wr*64 + mi*16 + l4*4;
                int b = pt >> 10, p = pt & 1023;
                size_t hb = (size_t)(b*NHEAD + h)*HD*HW;
                #pragma unroll
                for (int ni = 0; ni < 4; ++ni) {
                    int d = ni*16 + l15;
                    ushort4_t pk;
                    pk.x = f2bf(acc[mi][ni][0]);
                    pk.y = f2bf(acc[mi][ni][1]);
                    pk.z = f2bf(acc[mi][ni][2]);
                    pk.w = f2bf(acc[mi][ni][3]);
                    *(ushort4_t*)&VTt[hb + (size_t)d*HW + p] = pk;
                }
            }
        }
    } else {
        #pragma unroll
        for (int mi = 0; mi < 4; ++mi)
            #pragma unroll
            for (int ni = 0; ni < 4; ++ni)
                #pragma unroll
                for (int r = 0; r < 4; ++r) {
                    int row = tm + wr*64 + mi*16 + l4*4 + r;
                    int col = tn + wc*64 + ni*16 + l15;
                    C[(size_t)row*(128*NTILES) + col] = acc[mi][ni][r];
                }
    }
}

// ---------------- flash attention: 32 q/wave, 2-buffer counted-vmcnt, swizzled LDS ----------------
// grid 384 (8 qtiles x 48 bh, XCD-swizzled); 4 waves; wave: 32 q (2 frags), kv tiles of 64
__global__ __launch_bounds__(256) void attn_kernel(const ushort_t* __restrict__ Q,
                                                   const ushort_t* __restrict__ Kt,
                                                   const ushort_t* __restrict__ VT,
                                                   ushort_t* __restrict__ Ao) {
    __shared__ ushort_t Kb[2][64*64];
    __shared__ ushort_t Vb[2][64*64];
    __shared__ ushort_t P[4][32][72];
    int flat = blockIdx.x;                 // 384
    int swz = (flat & 7) * 48 + (flat >> 3);
    int bh = swz >> 3;
    int qtile = swz & 7;
    int w = threadIdx.x >> 6, lane = threadIdx.x & 63;
    int l15 = lane & 15, l4 = lane >> 4;
    int qbase = qtile * 128 + w * 32;      // 32-aligned
    int q0 = qbase + l15, q1 = q0 + 16;
    int qr = qbase >> 5;                   // wave-uniform grid row
    const ushort_t* Qh = Q + (size_t)bh * HW * HD;
    const ushort_t* Kh = Kt + (size_t)bh * HW * HD;
    const ushort_t* Vh = VT + (size_t)bh * HD * HW;
    short8 aq0_0 = *(const short8*)&Qh[(size_t)q0*64 + l4*8];
    short8 aq1_0 = *(const short8*)&Qh[(size_t)q0*64 + 32 + l4*8];
    short8 aq0_1 = *(const short8*)&Qh[(size_t)q1*64 + l4*8];
    short8 aq1_1 = *(const short8*)&Qh[(size_t)q1*64 + 32 + l4*8];
    unsigned pat0 = (l15 == 0) ? 3u : (7u << (l15 - 1));   // cols l15-1..l15+1
    unsigned pat1 = 7u << (l15 + 15);                      // cols l15+15..l15+17 (bit32 clipped)
    float m0 = -1e30f, ls0 = 0.f, m1 = -1e30f, ls1 = 0.f;
    f32x4 oacc0[4] = {}, oacc1[4] = {};

    auto stage = [&](int bufi, int kv) {
        #pragma unroll
        for (int is = 0; is < 2; ++is) {
            int c = is*256 + w*64 + lane;
            int row = c >> 3;
            int col16 = (c & 7) ^ (row & 7);
            const ushort_t* ga = Kh + (size_t)(kv + row)*64 + col16*8;
            __builtin_amdgcn_global_load_lds((const __attribute__((address_space(1))) void*)ga,
                (__attribute__((address_space(3))) void*)(&Kb[bufi][(size_t)(is*256 + w*64)*8]), 16, 0, 0);
            const ushort_t* gv = Vh + (size_t)row*HW + kv + col16*8;
            __builtin_amdgcn_global_load_lds((const __attribute__((address_space(1))) void*)gv,
                (__attribute__((address_space(3))) void*)(&Vb[bufi][(size_t)(is*256 + w*64)*8]), 16, 0, 0);
        }
    };

    stage(0, 0); stage(1, 64);

    for (int t = 0; t < 16; ++t) {
        if (t < 15) { asm volatile("s_waitcnt vmcnt(4)" ::: "memory"); }
        else        { asm volatile("s_waitcnt vmcnt(0)" ::: "memory"); }
        __builtin_amdgcn_s_barrier();
        int cur = t & 1;
        int kv = t * 64;
        int sw = l15 & 7;
        // ---- QK^T for both q-fragments (K fragments shared) ----
        f32x4 s0[4], s1[4];
        #pragma unroll
        for (int st = 0; st < 4; ++st) {
            int krow = st*16 + l15;
            short8 bk0 = *(const short8*)&Kb[cur][(size_t)krow*64 + (size_t)((l4 ^ sw))*8];
            short8 bk1 = *(const short8*)&Kb[cur][(size_t)krow*64 + (size_t)(((4+l4) ^ sw))*8];
            f32x4 z0 = {}, z1 = {};
            z0 = __builtin_amdgcn_mfma_f32_16x16x32_bf16(bk0, aq0_0, z0, 0, 0, 0);
            z0 = __builtin_amdgcn_mfma_f32_16x16x32_bf16(bk1, aq1_0, z0, 0, 0, 0);
            z1 = __builtin_amdgcn_mfma_f32_16x16x32_bf16(bk0, aq0_1, z1, 0, 0, 0);
            z1 = __builtin_amdgcn_mfma_f32_16x16x32_bf16(bk1, aq1_1, z1, 0, 0, 0);
            s0[st] = z0; s1[st] = z1;
        }
        // ---- V fragments (shared) ----
        short8 va0[4], va1[4];
        #pragma unroll
        for (int dt = 0; dt < 4; ++dt) {
            int vrow = dt*16 + l15;
            va0[dt] = *(const short8*)&Vb[cur][(size_t)vrow*64 + (size_t)((l4 ^ sw))*8];
            va1[dt] = *(const short8*)&Vb[cur][(size_t)vrow*64 + (size_t)(((4+l4) ^ sw))*8];
        }
        // ---- mask (only tiles overlapping rows qr-1..qr+1) ----
        int dr = qr - (kv >> 5);
        if (dr >= -1 && dr <= 2) {
            u64 tm0 = 0, tm1 = 0;
            if (dr <= 1) { tm0 |= (u64)pat0; tm1 |= (u64)pat1; }
            if (dr >= 0) { tm0 |= ((u64)pat0) << 32; tm1 |= ((u64)pat1) << 32; }
            u64 sub0 = tm0 >> (l4*4), sub1 = tm1 >> (l4*4);
            #pragma unroll
            for (int st = 0; st < 4; ++st)
                #pragma unroll
                for (int i = 0; i < 4; ++i) {
                    if ((sub0 >> (st*16 + i)) & 1) s0[st][i] = -1e30f;
                    if ((sub1 >> (st*16 + i)) & 1) s1[st][i] = -1e30f;
                }
        }
        // ---- softmax frag0 ----
        {
            float vmax = fmaxf(
                fmaxf(fmaxf(fmaxf(s0[0][0], s0[0][1]), fmaxf(s0[0][2], s0[0][3])),
                      fmaxf(fmaxf(s0[1][0], s0[1][1]), fmaxf(s0[1][2], s0[1][3]))),
                fmaxf(fmaxf(fmaxf(s0[2][0], s0[2][1]), fmaxf(s0[2][2], s0[2][3])),
                      fmaxf(fmaxf(s0[3][0], s0[3][1]), fmaxf(s0[3][2], s0[3][3]))));
            vmax = fmaxf(vmax, __shfl_xor(vmax, 16, 64));
            vmax = fmaxf(vmax, __shfl_xor(vmax, 32, 64));
            if (__any(vmax - m0 > 8.f)) {
                float mn = fmaxf(m0, vmax);
                float sf = ex2(m0 - mn);
                ls0 *= sf;
                #pragma unroll
                for (int dt = 0; dt < 4; ++dt)
                    #pragma unroll
                    for (int i = 0; i < 4; ++i) oacc0[dt][i] *= sf;
                m0 = mn;
            }
            float ls = 0.f;
            #pragma unroll
            for (int st = 0; st < 4; ++st) {
                float p0 = ex2(s0[st][0] - m0), p1 = ex2(s0[st][1] - m0);
                float p2 = ex2(s0[st][2] - m0), p3 = ex2(s0[st][3] - m0);
                ls += (p0 + p1) + (p2 + p3);
                uint2 pk; pk.x = cvtpk(p0, p1); pk.y = cvtpk(p2, p3);
                *(uint2*)&P[w][l15][st*16 + l4*4] = pk;
            }
            ls += __shfl_xor(ls, 16, 64);
            ls += __shfl_xor(ls, 32, 64);
            ls0 += ls;
        }
        // ---- softmax frag1 ----
        {
            float vmax = fmaxf(
                fmaxf(fmaxf(fmaxf(s1[0][0], s1[0][1]), fmaxf(s1[0][2], s1[0][3])),
                      fmaxf(fmaxf(s1[1][0], s1[1][1]), fmaxf(s1[1][2], s1[1][3]))),
                fmaxf(fmaxf(fmaxf(s1[2][0], s1[2][1]), fmaxf(s1[2][2], s1[2][3])),
                      fmaxf(fmaxf(s1[3][0], s1[3][1]), fmaxf(s1[3][2], s1[3][3]))));
            vmax = fmaxf(vmax, __shfl_xor(vmax, 16, 64));
            vmax = fmaxf(vmax, __shfl_xor(vmax, 32, 64));
            if (__any(vmax - m1 > 8.f)) {
                float mn = fmaxf(m1, vmax);
                float sf = ex2(m1 - mn);
                ls1 *= sf;
                #pragma unroll
                for (int dt = 0; dt < 4; ++dt)
                    #pragma unroll
                    for (int i = 0; i < 4; ++i) oacc1[dt][i] *= sf;
                m1 = mn;
            }
            float ls = 0.f;
            #pragma unroll
            for (int st = 0; st < 4; ++st) {
                float p0 = ex2(s1[st][0] - m1), p1 = ex2(s1[st][1] - m1);
                float p2 = ex2(s1[st][2] - m1), p3 = ex2(s1[st][3] - m1);
                ls += (p0 + p1) + (p2 + p3);
                uint2 pk; pk.x = cvtpk(p0, p1); pk.y = cvtpk(p2, p3);
                *(uint2*)&P[w][16 + l15][st*16 + l4*4] = pk;
            }
            ls += __shfl_xor(ls, 16, 64);
            ls += __shfl_xor(ls, 32, 64);
            ls1 += ls;
        }
        // ---- PV for both fragments (V fragments shared) ----
        short8 pf0_0 = *(const short8*)&P[w][l15][l4*8];
        short8 pf1_0 = *(const short8*)&P[w][l15][32 + l4*8];
        short8 pf0_1 = *(const short8*)&P[w][16 + l15][l4*8];
        short8 pf1_1 = *(const short8*)&P[w][16 + l15][32 + l4*8];
        #pragma unroll
        for (int dt = 0; dt < 4; ++dt) {
            oacc0[dt] = __builtin_amdgcn_mfma_f32_16x16x32_bf16(va0[dt], pf0_0, oacc0[dt], 0, 0, 0);
            oacc0[dt] = __builtin_amdgcn_mfma_f32_16x16x32_bf16(va1[dt], pf1_0, oacc0[dt], 0, 0, 0);
            oacc1[dt] = __builtin_amdgcn_mfma_f32_16x16x32_bf16(va0[dt], pf0_1, oacc1[dt], 0, 0, 0);
            oacc1[dt] = __builtin_amdgcn_mfma_f32_16x16x32_bf16(va1[dt], pf1_1, oacc1[dt], 0, 0, 0);
        }
        __builtin_amdgcn_s_barrier();
        if (t < 14) stage(cur, (t + 2) * 64);
    }
    int b = bh / NHEAD, h = bh % NHEAD;
    float rl0 = 1.f / ls0, rl1 = 1.f / ls1;
    size_t ob0 = ((size_t)b*HW + q0)*D_MODEL + h*64;
    size_t ob1 = ((size_t)b*HW + q1)*D_MODEL + h*64;
    #pragma unroll
    for (int dt = 0; dt < 4; ++dt) {
        uint2 pk0, pk1;
        pk0.x = cvtpk(oacc0[dt][0]*rl0, oacc0[dt][1]*rl0);
        pk0.y = cvtpk(oacc0[dt][2]*rl0, oacc0[dt][3]*rl0);
        pk1.x = cvtpk(oacc1[dt][0]*rl1, oacc1[dt][1]*rl1);
        pk1.y = cvtpk(oacc1[dt][2]*rl1, oacc1[dt][3]*rl1);
        *(uint2*)&Ao[ob0 + dt*16 + l4*4] = pk0;
        *(uint2*)&Ao[ob1 + dt*16 + l4*4] = pk1;
    }
}

extern "C" void kernel_launch(void* const* d_in, const int* in_sizes, int n_in,
                              void* d_out, int out_size, void* d_ws, size_t ws_size,
                              hipStream_t stream) {
    const float* x      = (const float*)d_in[0];
    const float* w_qkv  = (const float*)d_in[1];
    const float* w_out  = (const float*)d_in[2];
    const float* gamma  = (const float*)d_in[3];
    float* out = (float*)d_out;

    char* ws = (char*)d_ws;
    size_t off = 0;
    auto alloc = [&](size_t bytes) { char* p = ws + off; off += (bytes + 255) & ~255ull; return p; };
    ushort_t* xn   = (ushort_t*)alloc((size_t)TOK*D_MODEL*2);
    ushort_t* wq   = (ushort_t*)alloc((size_t)QKV_N*D_MODEL*2);
    ushort_t* wo   = (ushort_t*)alloc((size_t)D_MODEL*D_MODEL*2);
    float* sint    = (float*)alloc((size_t)HW*32*4);
    float* cost    = (float*)alloc((size_t)HW*32*4);
    ushort_t* Qr   = (ushort_t*)alloc((size_t)BH*HW*HD*2);
    ushort_t* Kr   = (ushort_t*)alloc((size_t)BH*HW*HD*2);
    ushort_t* VTt  = (ushort_t*)alloc((size_t)BH*HD*HW*2);
    ushort_t* Ao   = (ushort_t*)alloc((size_t)TOK*D_MODEL*2);

    prep_kernel<<<3456, 256, 0, stream>>>(x, gamma, xn, w_qkv, wq, w_out, wo, sint, cost);
    gemm128<18,0><<<576, 256, 0, stream>>>(xn, wq, sint, cost, Qr, Kr, VTt, nullptr);
    attn_kernel<<<384, 256, 0, stream>>>(Qr, Kr, VTt, Ao);
    gemm128<6,1><<<192, 256, 0, stream>>>(Ao, wo, nullptr, nullptr, nullptr, nullptr, nullptr, out);
}